// Round 1
// baseline (1105.944 us; speedup 1.0000x reference)
//
#include <hip/hip_runtime.h>
#include <math.h>

#define H 128
#define ED 16

__device__ __forceinline__ float wsum(float v) {
#pragma unroll
    for (int o = 32; o > 0; o >>= 1) v += __shfl_xor(v, o, 64);
    return v;
}
__device__ __forceinline__ float wmax(float v) {
#pragma unroll
    for (int o = 32; o > 0; o >>= 1) v = fmaxf(v, __shfl_xor(v, o, 64));
    return v;
}

__global__ void k_hist(const int* __restrict__ idx, int* __restrict__ cnt, int E) {
    int e = blockIdx.x * 256 + threadIdx.x;
    if (e < E) atomicAdd(&cnt[idx[e]], 1);
}

__global__ void k_scan_blocks(const int* __restrict__ cnt, int* __restrict__ rowstart,
                              int* __restrict__ partials, int n) {
    __shared__ int tmp[256];
    int t = threadIdx.x;
    int i = blockIdx.x * 256 + t;
    int v = (i < n) ? cnt[i] : 0;
    tmp[t] = v;
    __syncthreads();
#pragma unroll
    for (int o = 1; o < 256; o <<= 1) {
        int x = (t >= o) ? tmp[t - o] : 0;
        __syncthreads();
        if (t >= o) tmp[t] += x;
        __syncthreads();
    }
    int incl = tmp[t];
    if (i < n) rowstart[i] = incl - v;          // block-local exclusive
    if (t == 255) partials[blockIdx.x] = incl;  // block total
}

__global__ void k_scan_partials(int* __restrict__ partials, int nb) {
    __shared__ int tmp[512];
    int t = threadIdx.x;
    int v = (t < nb) ? partials[t] : 0;
    tmp[t] = v;
    __syncthreads();
#pragma unroll
    for (int o = 1; o < 512; o <<= 1) {
        int x = (t >= o) ? tmp[t - o] : 0;
        __syncthreads();
        if (t >= o) tmp[t] += x;
        __syncthreads();
    }
    if (t < nb) partials[t] = tmp[t] - v;  // exclusive block offsets
}

__global__ void k_add_offsets(int* __restrict__ rowstart, const int* __restrict__ partials,
                              int n, int E) {
    int i = blockIdx.x * 256 + threadIdx.x;
    if (i < n) rowstart[i] += partials[blockIdx.x];
    if (i == 0) rowstart[n] = E;
}

__global__ void k_scatter(const int* __restrict__ idx, const int* __restrict__ ptype,
                          const float* __restrict__ pw, const int* __restrict__ rowstart,
                          int* __restrict__ cursor, int* __restrict__ csr_col,
                          float* __restrict__ csr_s1, int E) {
    int e = blockIdx.x * 256 + threadIdx.x;
    if (e >= E) return;
    int r = idx[e], c = idx[E + e];
    int pos = atomicAdd(&cursor[r], 1);
    int d = rowstart[r] + pos;
    csr_col[d] = c;
    csr_s1[d] = pw[ptype[e]];
}

// One wave per row. Lanes = edges for score phase; lanes = feature dim (float2) for
// the v-accumulate phase. No atomics on the output.
__global__ __launch_bounds__(256) void k_attn(
    const float* __restrict__ q, const float* __restrict__ k, const float* __restrict__ v,
    const float* __restrict__ eigs, const float* __restrict__ lambda0,
    const int* __restrict__ rowstart, const int* __restrict__ csr_col,
    const float* __restrict__ csr_s1, float* __restrict__ csr_s0,
    float* __restrict__ out, int N) {
    int lane = threadIdx.x & 63;
    int wv = threadIdx.x >> 6;
    int rowi = blockIdx.x * 4 + wv;
    if (rowi >= N) return;

    const float el0 = __expf(lambda0[0]);
    const float inv = 0.08838834764831845f;  // 1/sqrt(128)
    int start = rowstart[rowi], end = rowstart[rowi + 1];

    const float4* qrow = (const float4*)(q + (size_t)rowi * H);    // wave-uniform
    const float4* erow = (const float4*)(eigs + (size_t)rowi * ED);

    // Pass 1: per-edge scores s0 (q.k/sqrt(H) + e^l0 * eig.eig), track maxes
    float m0 = -INFINITY, m1 = -INFINITY;
    for (int e0 = start; e0 < end; e0 += 64) {
        int e = e0 + lane;
        bool act = e < end;
        float s0v = -INFINITY, s1v = -INFINITY;
        if (act) {
            int c = csr_col[e];
            s1v = csr_s1[e];
            const float4* krow = (const float4*)(k + (size_t)c * H);
            float x0 = 0.f, x1 = 0.f, x2 = 0.f, x3 = 0.f;
#pragma unroll 8
            for (int t = 0; t < H / 4; t++) {
                float4 qv = qrow[t], kv = krow[t];
                x0 = fmaf(qv.x, kv.x, x0);
                x1 = fmaf(qv.y, kv.y, x1);
                x2 = fmaf(qv.z, kv.z, x2);
                x3 = fmaf(qv.w, kv.w, x3);
            }
            const float4* crow = (const float4*)(eigs + (size_t)c * ED);
            float y0 = 0.f, y1 = 0.f, y2 = 0.f, y3 = 0.f;
#pragma unroll
            for (int t = 0; t < ED / 4; t++) {
                float4 ev = erow[t], cv = crow[t];
                y0 = fmaf(ev.x, cv.x, y0);
                y1 = fmaf(ev.y, cv.y, y1);
                y2 = fmaf(ev.z, cv.z, y2);
                y3 = fmaf(ev.w, cv.w, y3);
            }
            float x = (x0 + x1) + (x2 + x3);
            float y = (y0 + y1) + (y2 + y3);
            s0v = x * inv + el0 * y;
            csr_s0[e] = s0v;
        }
        m0 = fmaxf(m0, s0v);
        m1 = fmaxf(m1, s1v);
    }
    m0 = wmax(m0);
    m1 = wmax(m1);

    // Pass 2: softmax denominators for both channels
    float d0 = 0.f, d1 = 0.f;
    for (int e0 = start; e0 < end; e0 += 64) {
        int e = e0 + lane;
        if (e < end) {
            d0 += __expf(csr_s0[e] - m0);
            d1 += __expf(csr_s1[e] - m1);
        }
    }
    d0 = wsum(d0);
    d1 = wsum(d1);
    float r0 = (d0 > 0.f) ? 0.5f / d0 : 0.f;
    float r1 = (d1 > 0.f) ? 0.5f / d1 : 0.f;

    // Pass 3: out[row] = sum_e w_e * v[col_e]; lanes hold float2 of the 128-dim row
    float2 acc = make_float2(0.f, 0.f);
    const float2* v2 = (const float2*)v;
    for (int e0 = start; e0 < end; e0 += 64) {
        int cnt = min(64, end - e0);
        int c = 0;
        float w = 0.f;
        if (lane < cnt) {
            int e = e0 + lane;
            c = csr_col[e];
            w = __expf(csr_s0[e] - m0) * r0 + __expf(csr_s1[e] - m1) * r1;
        }
        for (int j = 0; j < cnt; j++) {
            float wj = __shfl(w, j, 64);
            int cj = __shfl(c, j, 64);
            float2 vv = v2[(size_t)cj * (H / 2) + lane];
            acc.x = fmaf(wj, vv.x, acc.x);
            acc.y = fmaf(wj, vv.y, acc.y);
        }
    }
    ((float2*)out)[(size_t)rowi * (H / 2) + lane] = acc;
}

extern "C" void kernel_launch(void* const* d_in, const int* in_sizes, int n_in,
                              void* d_out, int out_size, void* d_ws, size_t ws_size,
                              hipStream_t stream) {
    const float* q = (const float*)d_in[0];
    const float* k = (const float*)d_in[1];
    const float* v = (const float*)d_in[2];
    const float* eigs = (const float*)d_in[3];
    const float* lambda0 = (const float*)d_in[4];
    const float* pw = (const float*)d_in[5];
    const int* indices = (const int*)d_in[6];
    const int* ptype = (const int*)d_in[7];
    float* out = (float*)d_out;

    int N = in_sizes[0] / H;
    int E = in_sizes[6] / 2;

    char* ws = (char*)d_ws;
    int* rowcount = (int*)ws;            // N  (zeroed)
    int* cursor = rowcount + N;          // N  (zeroed)
    int* rowstart = cursor + N;          // N+1
    int* partials = rowstart + (N + 1);  // 512
    size_t off = ((size_t)(2 * N + (N + 1) + 512) * 4 + 15) & ~(size_t)15;
    int* csr_col = (int*)(ws + off);
    off += (size_t)E * 4;
    float* csr_s1 = (float*)(ws + off);
    off += (size_t)E * 4;
    float* csr_s0 = (float*)(ws + off);

    hipMemsetAsync(rowcount, 0, (size_t)2 * N * sizeof(int), stream);

    int nbE = (E + 255) / 256;
    int nbN = (N + 255) / 256;  // 391 <= 512, fits single-block partials scan
    k_hist<<<nbE, 256, 0, stream>>>(indices, rowcount, E);
    k_scan_blocks<<<nbN, 256, 0, stream>>>(rowcount, rowstart, partials, N);
    k_scan_partials<<<1, 512, 0, stream>>>(partials, nbN);
    k_add_offsets<<<nbN, 256, 0, stream>>>(rowstart, partials, N, E);
    k_scatter<<<nbE, 256, 0, stream>>>(indices, ptype, pw, rowstart, cursor, csr_col,
                                       csr_s1, E);
    k_attn<<<(N + 3) / 4, 256, 0, stream>>>(q, k, v, eigs, lambda0, rowstart, csr_col,
                                            csr_s1, csr_s0, out, N);
}

// Round 2
// 1005.236 us; speedup vs baseline: 1.1002x; 1.1002x over previous
//
#include <hip/hip_runtime.h>
#include <math.h>

#define H 128
#define ED 16

__device__ __forceinline__ float wsum64(float v) {
#pragma unroll
    for (int o = 32; o > 0; o >>= 1) v += __shfl_xor(v, o, 64);
    return v;
}
__device__ __forceinline__ float wmax64(float v) {
#pragma unroll
    for (int o = 32; o > 0; o >>= 1) v = fmaxf(v, __shfl_xor(v, o, 64));
    return v;
}

// Pass A: per-edge rank within its destination row (single atomic pass).
__global__ void k_rank(const int* __restrict__ idx, int* __restrict__ cnt,
                       int* __restrict__ rank, int E) {
    int e = blockIdx.x * 256 + threadIdx.x;
    if (e < E) rank[e] = atomicAdd(&cnt[idx[e]], 1);
}

__global__ void k_scan_blocks(const int* __restrict__ cnt, int* __restrict__ rowstart,
                              int* __restrict__ partials, int n) {
    __shared__ int tmp[256];
    int t = threadIdx.x;
    int i = blockIdx.x * 256 + t;
    int v = (i < n) ? cnt[i] : 0;
    tmp[t] = v;
    __syncthreads();
#pragma unroll
    for (int o = 1; o < 256; o <<= 1) {
        int x = (t >= o) ? tmp[t - o] : 0;
        __syncthreads();
        if (t >= o) tmp[t] += x;
        __syncthreads();
    }
    int incl = tmp[t];
    if (i < n) rowstart[i] = incl - v;
    if (t == 255) partials[blockIdx.x] = incl;
}

__global__ void k_scan_partials(int* __restrict__ partials, int nb) {
    __shared__ int tmp[512];
    int t = threadIdx.x;
    int v = (t < nb) ? partials[t] : 0;
    tmp[t] = v;
    __syncthreads();
#pragma unroll
    for (int o = 1; o < 512; o <<= 1) {
        int x = (t >= o) ? tmp[t - o] : 0;
        __syncthreads();
        if (t >= o) tmp[t] += x;
        __syncthreads();
    }
    if (t < nb) partials[t] = tmp[t] - v;
}

__global__ void k_add_offsets(int* __restrict__ rowstart, const int* __restrict__ partials,
                              int n, int E) {
    int i = blockIdx.x * 256 + threadIdx.x;
    if (i < n) rowstart[i] += partials[blockIdx.x];
    if (i == 0) rowstart[n] = E;
}

// Pass B: atomic-free placement using precomputed ranks.
__global__ void k_place(const int* __restrict__ idx, const int* __restrict__ ptype,
                        const float* __restrict__ pw, const int* __restrict__ rowstart,
                        const int* __restrict__ rank, int* __restrict__ csr_col,
                        float* __restrict__ csr_s1, int E) {
    int e = blockIdx.x * 256 + threadIdx.x;
    if (e >= E) return;
    int r = idx[e];
    int d = rowstart[r] + rank[e];
    csr_col[d] = idx[E + e];
    csr_s1[d] = pw[ptype[e]];
}

// One wave per row. Half-wave (32 lanes x float4) per edge for coalesced k/v row
// reads; scores/cols/path-bias register-resident (deg <= 256; fallback otherwise).
__global__ __launch_bounds__(256) void k_attn(
    const float* __restrict__ q, const float* __restrict__ k, const float* __restrict__ v,
    const float* __restrict__ eigs, const float* __restrict__ lambda0,
    const int* __restrict__ rowstart, const int* __restrict__ csr_col,
    const float* __restrict__ csr_s1, float* __restrict__ spill,
    float* __restrict__ out, int N) {
    const int lane = threadIdx.x & 63;
    const int hf = lane >> 5;   // half-wave index
    const int sub = lane & 31;  // lane within half
    const int rowi = blockIdx.x * 4 + (threadIdx.x >> 6);
    if (rowi >= N) return;

    const float el0 = __expf(lambda0[0]);
    const float inv = 0.08838834764831845f;  // 1/sqrt(128)
    const int start = rowstart[rowi];
    const int deg = rowstart[rowi + 1] - start;

    const float4* q4 = (const float4*)q;
    const float4* k4 = (const float4*)k;
    const float4* v4 = (const float4*)v;
    const float4* e4 = (const float4*)eigs;

    if (deg <= 256) {
        float4 qf = q4[(size_t)rowi * 32 + sub];
        float4 ef = make_float4(0.f, 0.f, 0.f, 0.f);
        if (sub < 4) ef = e4[(size_t)rowi * 4 + sub];

        int c[4];
        float s1v[4], s0v[4], w[4];
#pragma unroll
        for (int s = 0; s < 4; s++) {
            int e = start + s * 64 + lane;
            bool val = (s * 64 + lane) < deg;
            c[s] = val ? csr_col[e] : 0;
            s1v[s] = val ? csr_s1[e] : -INFINITY;
            s0v[s] = -INFINITY;
        }
        const int npairs = (deg + 1) >> 1;

        // Pass 1: scores. Half-wave computes one edge's q.k (+ eig bias) per iter.
#pragma unroll
        for (int s = 0; s < 4; s++) {
            int i1 = min(npairs, (s + 1) * 32);
#pragma unroll 2
            for (int i = s * 32; i < i1; i++) {
                int rel = 2 * i + hf;
                int cm = __shfl(c[s], 2 * (i & 31) + hf, 64);
                float contrib = 0.f;
                if (rel < deg) {
                    float4 kv = k4[(size_t)cm * 32 + sub];
                    contrib = (qf.x * kv.x + qf.y * kv.y + qf.z * kv.z + qf.w * kv.w) * inv;
                    if (sub < 4) {
                        float4 ev = e4[(size_t)cm * 4 + sub];
                        contrib += (ef.x * ev.x + ef.y * ev.y + ef.z * ev.z + ef.w * ev.w) * el0;
                    }
                }
#pragma unroll
                for (int o = 1; o < 32; o <<= 1) contrib += __shfl_xor(contrib, o, 64);
                float cand = __shfl(contrib, (lane & 1) << 5, 64);
                if ((lane >> 1) == (i & 31) && (s * 64 + lane) < deg) s0v[s] = cand;
            }
        }

        // Pass 2 (registers only): maxes, denominators, per-edge weights.
        float m0 = -INFINITY, m1 = -INFINITY;
#pragma unroll
        for (int s = 0; s < 4; s++) {
            m0 = fmaxf(m0, s0v[s]);
            m1 = fmaxf(m1, s1v[s]);
        }
        m0 = wmax64(m0);
        m1 = wmax64(m1);
        float d0 = 0.f, d1 = 0.f;
#pragma unroll
        for (int s = 0; s < 4; s++) {
            if (s * 64 + lane < deg) {
                d0 += __expf(s0v[s] - m0);
                d1 += __expf(s1v[s] - m1);
            }
        }
        d0 = wsum64(d0);
        d1 = wsum64(d1);
        float r0 = (d0 > 0.f) ? 0.5f / d0 : 0.f;
        float r1 = (d1 > 0.f) ? 0.5f / d1 : 0.f;
#pragma unroll
        for (int s = 0; s < 4; s++) {
            w[s] = (s * 64 + lane < deg)
                       ? (__expf(s0v[s] - m0) * r0 + __expf(s1v[s] - m1) * r1)
                       : 0.f;
        }

        // Pass 3: half-wave float4 v accumulate, 2 edges per iteration.
        float4 acc = make_float4(0.f, 0.f, 0.f, 0.f);
#pragma unroll
        for (int s = 0; s < 4; s++) {
            int i1 = min(npairs, (s + 1) * 32);
#pragma unroll 4
            for (int i = s * 32; i < i1; i++) {
                int rel = 2 * i + hf;
                int src = 2 * (i & 31) + hf;
                float wj = __shfl(w[s], src, 64);
                int cj = __shfl(c[s], src, 64);
                if (rel < deg) {
                    float4 vv = v4[(size_t)cj * 32 + sub];
                    acc.x = fmaf(wj, vv.x, acc.x);
                    acc.y = fmaf(wj, vv.y, acc.y);
                    acc.z = fmaf(wj, vv.z, acc.z);
                    acc.w = fmaf(wj, vv.w, acc.w);
                }
            }
        }
        acc.x += __shfl_xor(acc.x, 32, 64);
        acc.y += __shfl_xor(acc.y, 32, 64);
        acc.z += __shfl_xor(acc.z, 32, 64);
        acc.w += __shfl_xor(acc.w, 32, 64);
        if (hf == 0) ((float4*)out)[(size_t)rowi * 32 + sub] = acc;
        return;
    }

    // ---- Fallback (deg > 256): lane-per-edge, scores spilled to workspace. ----
    int end = start + deg;
    const float4* qrow = (const float4*)(q + (size_t)rowi * H);
    const float4* erow = (const float4*)(eigs + (size_t)rowi * ED);
    float m0 = -INFINITY, m1 = -INFINITY;
    for (int e0 = start; e0 < end; e0 += 64) {
        int e = e0 + lane;
        float s0f = -INFINITY, s1f = -INFINITY;
        if (e < end) {
            int cc = csr_col[e];
            s1f = csr_s1[e];
            const float4* krow = (const float4*)(k + (size_t)cc * H);
            float x = 0.f;
#pragma unroll 8
            for (int t = 0; t < H / 4; t++) {
                float4 qv = qrow[t], kv = krow[t];
                x += qv.x * kv.x + qv.y * kv.y + qv.z * kv.z + qv.w * kv.w;
            }
            const float4* crow = (const float4*)(eigs + (size_t)cc * ED);
            float y = 0.f;
#pragma unroll
            for (int t = 0; t < ED / 4; t++) {
                float4 ev = erow[t], cv = crow[t];
                y += ev.x * cv.x + ev.y * cv.y + ev.z * cv.z + ev.w * cv.w;
            }
            s0f = x * inv + el0 * y;
            spill[e] = s0f;
        }
        m0 = fmaxf(m0, s0f);
        m1 = fmaxf(m1, s1f);
    }
    m0 = wmax64(m0);
    m1 = wmax64(m1);
    float d0 = 0.f, d1 = 0.f;
    for (int e0 = start; e0 < end; e0 += 64) {
        int e = e0 + lane;
        if (e < end) {
            d0 += __expf(spill[e] - m0);
            d1 += __expf(csr_s1[e] - m1);
        }
    }
    d0 = wsum64(d0);
    d1 = wsum64(d1);
    float r0 = (d0 > 0.f) ? 0.5f / d0 : 0.f;
    float r1 = (d1 > 0.f) ? 0.5f / d1 : 0.f;
    float2 acc2 = make_float2(0.f, 0.f);
    const float2* v2 = (const float2*)v;
    for (int e0 = start; e0 < end; e0 += 64) {
        int cnt2 = min(64, end - e0);
        int cc = 0;
        float wv = 0.f;
        if (lane < cnt2) {
            int e = e0 + lane;
            cc = csr_col[e];
            wv = __expf(spill[e] - m0) * r0 + __expf(csr_s1[e] - m1) * r1;
        }
        for (int j = 0; j < cnt2; j++) {
            float wj = __shfl(wv, j, 64);
            int cj = __shfl(cc, j, 64);
            float2 vvv = v2[(size_t)cj * (H / 2) + lane];
            acc2.x = fmaf(wj, vvv.x, acc2.x);
            acc2.y = fmaf(wj, vvv.y, acc2.y);
        }
    }
    ((float2*)out)[(size_t)rowi * (H / 2) + lane] = acc2;
}

extern "C" void kernel_launch(void* const* d_in, const int* in_sizes, int n_in,
                              void* d_out, int out_size, void* d_ws, size_t ws_size,
                              hipStream_t stream) {
    const float* q = (const float*)d_in[0];
    const float* k = (const float*)d_in[1];
    const float* v = (const float*)d_in[2];
    const float* eigs = (const float*)d_in[3];
    const float* lambda0 = (const float*)d_in[4];
    const float* pw = (const float*)d_in[5];
    const int* indices = (const int*)d_in[6];
    const int* ptype = (const int*)d_in[7];
    float* out = (float*)d_out;

    int N = in_sizes[0] / H;
    int E = in_sizes[6] / 2;

    char* ws = (char*)d_ws;
    int* cnt = (int*)ws;                 // N (zeroed)
    int* rowstart = cnt + N;             // N+1
    int* partials = rowstart + (N + 1);  // 512
    size_t off = ((size_t)(N + (N + 1) + 512) * 4 + 15) & ~(size_t)15;
    int* rank = (int*)(ws + off);  // E ints; reused as float spill by k_attn fallback
    off += (size_t)E * 4;
    int* csr_col = (int*)(ws + off);
    off += (size_t)E * 4;
    float* csr_s1 = (float*)(ws + off);

    hipMemsetAsync(cnt, 0, (size_t)N * sizeof(int), stream);

    int nbE = (E + 255) / 256;
    int nbN = (N + 255) / 256;  // 391 <= 512: single-block partials scan OK
    k_rank<<<nbE, 256, 0, stream>>>(indices, cnt, rank, E);
    k_scan_blocks<<<nbN, 256, 0, stream>>>(cnt, rowstart, partials, N);
    k_scan_partials<<<1, 512, 0, stream>>>(partials, nbN);
    k_add_offsets<<<nbN, 256, 0, stream>>>(rowstart, partials, N, E);
    k_place<<<nbE, 256, 0, stream>>>(indices, ptype, pw, rowstart, rank, csr_col,
                                     csr_s1, E);
    k_attn<<<(N + 3) / 4, 256, 0, stream>>>(q, k, v, eigs, lambda0, rowstart, csr_col,
                                            csr_s1, (float*)rank, out, N);
}

// Round 3
// 862.174 us; speedup vs baseline: 1.2827x; 1.1659x over previous
//
#include <hip/hip_runtime.h>
#include <math.h>

#define H 128
#define ED 16
#define COLBITS 17
#define COLMASK 0x1FFFF

__device__ __forceinline__ float wsum64(float v) {
#pragma unroll
    for (int o = 32; o > 0; o >>= 1) v += __shfl_xor(v, o, 64);
    return v;
}
__device__ __forceinline__ float wmax64(float v) {
#pragma unroll
    for (int o = 32; o > 0; o >>= 1) v = fmaxf(v, __shfl_xor(v, o, 64));
    return v;
}

// Per-edge rank within its destination row (single atomic pass).
__global__ void k_rank(const int* __restrict__ idx, int* __restrict__ cnt,
                       int* __restrict__ rank, int E) {
    int e = blockIdx.x * 256 + threadIdx.x;
    if (e < E) rank[e] = atomicAdd(&cnt[idx[e]], 1);
}

__global__ void k_scan_blocks(const int* __restrict__ cnt, int* __restrict__ rowstart,
                              int* __restrict__ partials, int n) {
    __shared__ int tmp[256];
    int t = threadIdx.x;
    int i = blockIdx.x * 256 + t;
    int v = (i < n) ? cnt[i] : 0;
    tmp[t] = v;
    __syncthreads();
#pragma unroll
    for (int o = 1; o < 256; o <<= 1) {
        int x = (t >= o) ? tmp[t - o] : 0;
        __syncthreads();
        if (t >= o) tmp[t] += x;
        __syncthreads();
    }
    int incl = tmp[t];
    if (i < n) rowstart[i] = incl - v;
    if (t == 255) partials[blockIdx.x] = incl;
}

__global__ void k_scan_partials(int* __restrict__ partials, int nb) {
    __shared__ int tmp[512];
    int t = threadIdx.x;
    int v = (t < nb) ? partials[t] : 0;
    tmp[t] = v;
    __syncthreads();
#pragma unroll
    for (int o = 1; o < 512; o <<= 1) {
        int x = (t >= o) ? tmp[t - o] : 0;
        __syncthreads();
        if (t >= o) tmp[t] += x;
        __syncthreads();
    }
    if (t < nb) partials[t] = tmp[t] - v;
}

__global__ void k_add_offsets(int* __restrict__ rowstart, const int* __restrict__ partials,
                              int n, int E) {
    int i = blockIdx.x * 256 + threadIdx.x;
    if (i < n) rowstart[i] += partials[blockIdx.x];
    if (i == 0) rowstart[n] = E;
}

// Atomic-free placement; packed entry = (ptype << 17) | col  (col < 2^17).
__global__ void k_place(const int* __restrict__ idx, const int* __restrict__ ptype,
                        const int* __restrict__ rowstart, const int* __restrict__ rank,
                        int* __restrict__ csr, int E) {
    int e = blockIdx.x * 256 + threadIdx.x;
    if (e >= E) return;
    int r = idx[e];
    int d = rowstart[r] + rank[e];
    csr[d] = (ptype[e] << COLBITS) | idx[E + e];
}

// One wave per row. 16-lane groups, 4 edges in flight per iteration.
// Lane L = g*16+s16 owns edge eL = 4*s16+g (scores/weights layout); group g
// computes edge 4i+g at iteration i, so edge eL's score is produced in lane L's
// own group at iteration s16 -> no delivery shuffle needed.
__global__ __launch_bounds__(256) void k_attn(
    const float* __restrict__ q, const float* __restrict__ k, const float* __restrict__ v,
    const float* __restrict__ eigs, const float* __restrict__ lambda0,
    const float* __restrict__ pw, const int* __restrict__ rowstart,
    const int* __restrict__ csr, float* __restrict__ spill,
    float* __restrict__ out, int N) {
    const int lane = threadIdx.x & 63;
    const int g = lane >> 4;
    const int s16 = lane & 15;
    const int rowi = blockIdx.x * 4 + (threadIdx.x >> 6);
    if (rowi >= N) return;

    const float el0 = __expf(lambda0[0]);
    const float inv = 0.08838834764831845f;  // 1/sqrt(128)
    const int start = rowstart[rowi];
    const int deg = rowstart[rowi + 1] - start;

    const float4* q4 = (const float4*)q;
    const float4* k4 = (const float4*)k;
    const float4* v4 = (const float4*)v;
    const float4* e4 = (const float4*)eigs;

    if (deg <= 64) {
        const int eL = 4 * s16 + g;
        const bool val = eL < deg;
        int x = val ? csr[start + eL] : 0;
        int c0 = x & COLMASK;
        float s1v = val ? pw[(x >> COLBITS) & 7] : -INFINITY;

        float4 qa = q4[(size_t)rowi * 32 + s16];
        float4 qb = q4[(size_t)rowi * 32 + 16 + s16];
        float4 ea = make_float4(0.f, 0.f, 0.f, 0.f);
        if (s16 < 4) ea = e4[(size_t)rowi * 4 + s16];

        const int niter = (deg + 3) >> 2;

        // Pass 1: scores. Group g handles edge 4i+g; lane reads 32 B of k-row.
        float s0v = -INFINITY;
#pragma unroll 4
        for (int i = 0; i < niter; i++) {
            int rel = 4 * i + g;
            int cm = __shfl(c0, (g << 4) | i, 64);
            float p = 0.f;
            if (rel < deg) {
                float4 ka = k4[(size_t)cm * 32 + s16];
                float4 kb = k4[(size_t)cm * 32 + 16 + s16];
                p = (ka.x * qa.x + ka.y * qa.y + ka.z * qa.z + ka.w * qa.w +
                     kb.x * qb.x + kb.y * qb.y + kb.z * qb.z + kb.w * qb.w) * inv;
                if (s16 < 4) {
                    float4 ev = e4[(size_t)cm * 4 + s16];
                    p += el0 * (ea.x * ev.x + ea.y * ev.y + ea.z * ev.z + ea.w * ev.w);
                }
            }
#pragma unroll
            for (int o = 1; o < 16; o <<= 1) p += __shfl_xor(p, o, 64);
            if (s16 == i && val) s0v = p;
        }

        // Softmax (registers only).
        float m0 = wmax64(s0v);
        float m1 = wmax64(s1v);
        float p0 = val ? __expf(s0v - m0) : 0.f;
        float p1 = val ? __expf(s1v - m1) : 0.f;
        float d0 = wsum64(p0);
        float d1 = wsum64(p1);
        float r0 = (d0 > 0.f) ? 0.5f / d0 : 0.f;
        float r1 = (d1 > 0.f) ? 0.5f / d1 : 0.f;
        float w = p0 * r0 + p1 * r1;

        // Pass 3: weighted v accumulate, same group structure.
        float4 acc0 = make_float4(0.f, 0.f, 0.f, 0.f);
        float4 acc1 = make_float4(0.f, 0.f, 0.f, 0.f);
#pragma unroll 4
        for (int i = 0; i < niter; i++) {
            int rel = 4 * i + g;
            int src = (g << 4) | i;
            int cm = __shfl(c0, src, 64);
            float wj = __shfl(w, src, 64);
            if (rel < deg) {
                float4 va = v4[(size_t)cm * 32 + s16];
                float4 vb = v4[(size_t)cm * 32 + 16 + s16];
                acc0.x = fmaf(wj, va.x, acc0.x);
                acc0.y = fmaf(wj, va.y, acc0.y);
                acc0.z = fmaf(wj, va.z, acc0.z);
                acc0.w = fmaf(wj, va.w, acc0.w);
                acc1.x = fmaf(wj, vb.x, acc1.x);
                acc1.y = fmaf(wj, vb.y, acc1.y);
                acc1.z = fmaf(wj, vb.z, acc1.z);
                acc1.w = fmaf(wj, vb.w, acc1.w);
            }
        }
#pragma unroll
        for (int o = 16; o < 64; o <<= 1) {
            acc0.x += __shfl_xor(acc0.x, o, 64);
            acc0.y += __shfl_xor(acc0.y, o, 64);
            acc0.z += __shfl_xor(acc0.z, o, 64);
            acc0.w += __shfl_xor(acc0.w, o, 64);
            acc1.x += __shfl_xor(acc1.x, o, 64);
            acc1.y += __shfl_xor(acc1.y, o, 64);
            acc1.z += __shfl_xor(acc1.z, o, 64);
            acc1.w += __shfl_xor(acc1.w, o, 64);
        }
        if (g == 0) {
            ((float4*)out)[(size_t)rowi * 32 + s16] = acc0;
            ((float4*)out)[(size_t)rowi * 32 + 16 + s16] = acc1;
        }
        return;
    }

    // ---- Fallback (deg > 64): lane-per-edge, scores spilled to workspace. ----
    const int end = start + deg;
    const float4* qrow = (const float4*)(q + (size_t)rowi * H);
    const float4* erow = (const float4*)(eigs + (size_t)rowi * ED);
    float m0 = -INFINITY, m1 = -INFINITY;
    for (int e0 = start; e0 < end; e0 += 64) {
        int e = e0 + lane;
        float s0f = -INFINITY, s1f = -INFINITY;
        if (e < end) {
            int x = csr[e];
            int cc = x & COLMASK;
            s1f = pw[(x >> COLBITS) & 7];
            const float4* krow = (const float4*)(k + (size_t)cc * H);
            float xx = 0.f;
#pragma unroll 8
            for (int t = 0; t < H / 4; t++) {
                float4 qv = qrow[t], kv = krow[t];
                xx += qv.x * kv.x + qv.y * kv.y + qv.z * kv.z + qv.w * kv.w;
            }
            const float4* crow = (const float4*)(eigs + (size_t)cc * ED);
            float yy = 0.f;
#pragma unroll
            for (int t = 0; t < ED / 4; t++) {
                float4 ev = erow[t], cv = crow[t];
                yy += ev.x * cv.x + ev.y * cv.y + ev.z * cv.z + ev.w * cv.w;
            }
            s0f = xx * inv + el0 * yy;
            spill[e] = s0f;
        }
        m0 = fmaxf(m0, s0f);
        m1 = fmaxf(m1, s1f);
    }
    m0 = wmax64(m0);
    m1 = wmax64(m1);
    float d0 = 0.f, d1 = 0.f;
    for (int e0 = start; e0 < end; e0 += 64) {
        int e = e0 + lane;
        if (e < end) {
            int x = csr[e];
            d0 += __expf(spill[e] - m0);
            d1 += __expf(pw[(x >> COLBITS) & 7] - m1);
        }
    }
    d0 = wsum64(d0);
    d1 = wsum64(d1);
    float r0 = (d0 > 0.f) ? 0.5f / d0 : 0.f;
    float r1 = (d1 > 0.f) ? 0.5f / d1 : 0.f;
    float2 acc2 = make_float2(0.f, 0.f);
    const float2* v2 = (const float2*)v;
    for (int e0 = start; e0 < end; e0 += 64) {
        int cnt2 = min(64, end - e0);
        int cc = 0;
        float wv = 0.f;
        if (lane < cnt2) {
            int e = e0 + lane;
            int x = csr[e];
            cc = x & COLMASK;
            wv = __expf(spill[e] - m0) * r0 + __expf(pw[(x >> COLBITS) & 7] - m1) * r1;
        }
        for (int j = 0; j < cnt2; j++) {
            float wj = __shfl(wv, j, 64);
            int cj = __shfl(cc, j, 64);
            float2 vvv = v2[(size_t)cj * (H / 2) + lane];
            acc2.x = fmaf(wj, vvv.x, acc2.x);
            acc2.y = fmaf(wj, vvv.y, acc2.y);
        }
    }
    ((float2*)out)[(size_t)rowi * (H / 2) + lane] = acc2;
}

extern "C" void kernel_launch(void* const* d_in, const int* in_sizes, int n_in,
                              void* d_out, int out_size, void* d_ws, size_t ws_size,
                              hipStream_t stream) {
    const float* q = (const float*)d_in[0];
    const float* k = (const float*)d_in[1];
    const float* v = (const float*)d_in[2];
    const float* eigs = (const float*)d_in[3];
    const float* lambda0 = (const float*)d_in[4];
    const float* pw = (const float*)d_in[5];
    const int* indices = (const int*)d_in[6];
    const int* ptype = (const int*)d_in[7];
    float* out = (float*)d_out;

    int N = in_sizes[0] / H;
    int E = in_sizes[6] / 2;

    char* ws = (char*)d_ws;
    int* cnt = (int*)ws;                 // N (zeroed)
    int* rowstart = cnt + N;             // N+1
    int* partials = rowstart + (N + 1);  // 512
    size_t off = ((size_t)(N + (N + 1) + 512) * 4 + 15) & ~(size_t)15;
    int* rank = (int*)(ws + off);  // E ints; reused as float spill by k_attn fallback
    off += (size_t)E * 4;
    int* csr = (int*)(ws + off);   // E ints, packed (ptype<<17)|col

    hipMemsetAsync(cnt, 0, (size_t)N * sizeof(int), stream);

    int nbE = (E + 255) / 256;
    int nbN = (N + 255) / 256;  // 391 <= 512: single-block partials scan OK
    k_rank<<<nbE, 256, 0, stream>>>(indices, cnt, rank, E);
    k_scan_blocks<<<nbN, 256, 0, stream>>>(cnt, rowstart, partials, N);
    k_scan_partials<<<1, 512, 0, stream>>>(partials, nbN);
    k_add_offsets<<<nbN, 256, 0, stream>>>(rowstart, partials, N, E);
    k_place<<<nbE, 256, 0, stream>>>(indices, ptype, rowstart, rank, csr, E);
    k_attn<<<(N + 3) / 4, 256, 0, stream>>>(q, k, v, eigs, lambda0, pw, rowstart, csr,
                                            (float*)rank, out, N);
}

// Round 4
// 784.399 us; speedup vs baseline: 1.4099x; 1.0992x over previous
//
#include <hip/hip_runtime.h>
#include <math.h>

#define H 128
#define ED 16
#define COLBITS 17
#define COLMASK 0x1FFFF

__device__ __forceinline__ float wsum64(float v) {
#pragma unroll
    for (int o = 32; o > 0; o >>= 1) v += __shfl_xor(v, o, 64);
    return v;
}
__device__ __forceinline__ float wmax64(float v) {
#pragma unroll
    for (int o = 32; o > 0; o >>= 1) v = fmaxf(v, __shfl_xor(v, o, 64));
    return v;
}
__device__ __forceinline__ float bflo(unsigned u) { return __uint_as_float(u << 16); }
__device__ __forceinline__ float bfhi(unsigned u) { return __uint_as_float(u & 0xffff0000u); }
__device__ __forceinline__ unsigned short f2bf(float f) {  // RNE
    unsigned u = __float_as_uint(f);
    return (unsigned short)((u + 0x7fff + ((u >> 16) & 1)) >> 16);
}

// fp32 -> bf16 cast (RNE), 4 elements/thread.
__global__ void k_cast(const float4* __restrict__ src, ushort4* __restrict__ dst, int n4) {
    int i = blockIdx.x * 256 + threadIdx.x;
    if (i >= n4) return;
    float4 f = src[i];
    ushort4 o;
    o.x = f2bf(f.x);
    o.y = f2bf(f.y);
    o.z = f2bf(f.z);
    o.w = f2bf(f.w);
    dst[i] = o;
}

// Per-edge rank within its destination row (single atomic pass), 4 edges/thread.
__global__ void k_rank(const int* __restrict__ idx, int* __restrict__ cnt,
                       int* __restrict__ rank, int E) {
    int e = (blockIdx.x * 256 + threadIdx.x) * 4;
    if (e + 3 < E) {
        int4 r = *(const int4*)(idx + e);
        int4 o;
        o.x = atomicAdd(&cnt[r.x], 1);
        o.y = atomicAdd(&cnt[r.y], 1);
        o.z = atomicAdd(&cnt[r.z], 1);
        o.w = atomicAdd(&cnt[r.w], 1);
        *(int4*)(rank + e) = o;
    } else {
        for (; e < E; e++) rank[e] = atomicAdd(&cnt[idx[e]], 1);
    }
}

__global__ void k_scan_blocks(const int* __restrict__ cnt, int* __restrict__ rowstart,
                              int* __restrict__ partials, int n) {
    __shared__ int tmp[256];
    int t = threadIdx.x;
    int i = blockIdx.x * 256 + t;
    int v = (i < n) ? cnt[i] : 0;
    tmp[t] = v;
    __syncthreads();
#pragma unroll
    for (int o = 1; o < 256; o <<= 1) {
        int x = (t >= o) ? tmp[t - o] : 0;
        __syncthreads();
        if (t >= o) tmp[t] += x;
        __syncthreads();
    }
    int incl = tmp[t];
    if (i < n) rowstart[i] = incl - v;
    if (t == 255) partials[blockIdx.x] = incl;
}

__global__ void k_scan_partials(int* __restrict__ partials, int nb) {
    __shared__ int tmp[512];
    int t = threadIdx.x;
    int v = (t < nb) ? partials[t] : 0;
    tmp[t] = v;
    __syncthreads();
#pragma unroll
    for (int o = 1; o < 512; o <<= 1) {
        int x = (t >= o) ? tmp[t - o] : 0;
        __syncthreads();
        if (t >= o) tmp[t] += x;
        __syncthreads();
    }
    if (t < nb) partials[t] = tmp[t] - v;
}

__global__ void k_add_offsets(int* __restrict__ rowstart, const int* __restrict__ partials,
                              int n, int E) {
    int i = blockIdx.x * 256 + threadIdx.x;
    if (i < n) rowstart[i] += partials[blockIdx.x];
    if (i == 0) rowstart[n] = E;
}

// Atomic-free placement; packed entry = (ptype << 17) | col. 4 edges/thread.
__global__ void k_place(const int* __restrict__ idx, const int* __restrict__ ptype,
                        const int* __restrict__ rowstart, const int* __restrict__ rank,
                        int* __restrict__ csr, int E) {
    int e = (blockIdx.x * 256 + threadIdx.x) * 4;
    if (e + 3 < E) {
        int4 r = *(const int4*)(idx + e);
        int4 c = *(const int4*)(idx + E + e);
        int4 p = *(const int4*)(ptype + e);
        int4 rk = *(const int4*)(rank + e);
        csr[rowstart[r.x] + rk.x] = (p.x << COLBITS) | c.x;
        csr[rowstart[r.y] + rk.y] = (p.y << COLBITS) | c.y;
        csr[rowstart[r.z] + rk.z] = (p.z << COLBITS) | c.z;
        csr[rowstart[r.w] + rk.w] = (p.w << COLBITS) | c.w;
    } else {
        for (; e < E; e++)
            csr[rowstart[idx[e]] + rank[e]] = (ptype[e] << COLBITS) | idx[E + e];
    }
}

// One wave per row; 16-lane groups; k/v in bf16 (one 16B load = full 256B row per
// group). Column index loaded directly from csr each iteration (L1 group-broadcast)
// so the gather address chain has no cross-lane shuffle. deg<=128 register path.
__global__ __launch_bounds__(256) void k_attn(
    const float* __restrict__ q, const unsigned short* __restrict__ kb,
    const unsigned short* __restrict__ vb, const float* __restrict__ eigs,
    const float* __restrict__ lambda0, const float* __restrict__ pw,
    const int* __restrict__ rowstart, const int* __restrict__ csr,
    float* __restrict__ spill, float* __restrict__ out, int N) {
    const int lane = threadIdx.x & 63;
    const int g = lane >> 4;
    const int s16 = lane & 15;
    const int rowi = blockIdx.x * 4 + (threadIdx.x >> 6);
    if (rowi >= N) return;

    const float el0 = __expf(lambda0[0]);
    const float inv = 0.08838834764831845f;  // 1/sqrt(128)
    const int start = rowstart[rowi];
    const int deg = rowstart[rowi + 1] - start;

    const float4* q4 = (const float4*)q;
    const float4* e4 = (const float4*)eigs;

    if (deg == 0) {
        if (g == 0) {
            float4 z = make_float4(0.f, 0.f, 0.f, 0.f);
            ((float4*)out)[(size_t)rowi * 32 + s16 * 2] = z;
            ((float4*)out)[(size_t)rowi * 32 + s16 * 2 + 1] = z;
        }
        return;
    }

    if (deg <= 128) {
        // Lane L=(g<<4)|s16 owns edges e=64*slot+4*s16+g (slot 0,1).
        float s00 = -INFINITY, s01 = -INFINITY, t10 = -INFINITY, t11 = -INFINITY;
        {
            int e0 = 4 * s16 + g;
            if (e0 < deg) t10 = pw[(csr[start + e0] >> COLBITS) & 7];
            int e1 = 64 + 4 * s16 + g;
            if (e1 < deg) t11 = pw[(csr[start + e1] >> COLBITS) & 7];
        }
        float4 qa = q4[(size_t)rowi * 32 + s16 * 2];
        float4 qb = q4[(size_t)rowi * 32 + s16 * 2 + 1];
        float4 ea = make_float4(0.f, 0.f, 0.f, 0.f);
        if (s16 < 4) ea = e4[(size_t)rowi * 4 + s16];

        const int niter = (deg + 3) >> 2;

        // Pass 1: scores. Group g computes edge 4i+g at iteration i.
#pragma unroll 8
        for (int i = 0; i < niter; i++) {
            int rel = 4 * i + g;
            float p = 0.f;
            if (rel < deg) {
                int cm = csr[start + rel] & COLMASK;
                uint4 kr = *(const uint4*)(kb + (size_t)cm * H + s16 * 8);
                p = (qa.x * bflo(kr.x) + qa.y * bfhi(kr.x) + qa.z * bflo(kr.y) +
                     qa.w * bfhi(kr.y) + qb.x * bflo(kr.z) + qb.y * bfhi(kr.z) +
                     qb.z * bflo(kr.w) + qb.w * bfhi(kr.w)) * inv;
                if (s16 < 4) {
                    float4 ev = e4[(size_t)cm * 4 + s16];
                    p += el0 * (ea.x * ev.x + ea.y * ev.y + ea.z * ev.z + ea.w * ev.w);
                }
            }
#pragma unroll
            for (int o = 1; o < 16; o <<= 1) p += __shfl_xor(p, o, 64);
            if (s16 == (i & 15) && rel < deg) {
                if (i < 16) s00 = p;
                else s01 = p;
            }
        }

        // Softmax (registers only).
        float m0 = wmax64(fmaxf(s00, s01));
        float m1 = wmax64(fmaxf(t10, t11));
        float p00 = __expf(s00 - m0), p01 = __expf(s01 - m0);
        float p10 = __expf(t10 - m1), p11 = __expf(t11 - m1);
        float d0 = wsum64(p00 + p01);
        float d1 = wsum64(p10 + p11);
        float r0 = (d0 > 0.f) ? 0.5f / d0 : 0.f;
        float r1 = (d1 > 0.f) ? 0.5f / d1 : 0.f;
        float w0 = p00 * r0 + p10 * r1;
        float w1 = p01 * r0 + p11 * r1;

        // Pass 3: weighted v accumulate (bf16 rows), same group structure.
        float4 acc_a = make_float4(0.f, 0.f, 0.f, 0.f);
        float4 acc_b = make_float4(0.f, 0.f, 0.f, 0.f);
#pragma unroll 8
        for (int i = 0; i < niter; i++) {
            int rel = 4 * i + g;
            int src = (g << 4) | (i & 15);
            float wj = __shfl((i < 16) ? w0 : w1, src, 64);
            if (rel < deg) {
                int cm = csr[start + rel] & COLMASK;
                uint4 vr = *(const uint4*)(vb + (size_t)cm * H + s16 * 8);
                acc_a.x = fmaf(wj, bflo(vr.x), acc_a.x);
                acc_a.y = fmaf(wj, bfhi(vr.x), acc_a.y);
                acc_a.z = fmaf(wj, bflo(vr.y), acc_a.z);
                acc_a.w = fmaf(wj, bfhi(vr.y), acc_a.w);
                acc_b.x = fmaf(wj, bflo(vr.z), acc_b.x);
                acc_b.y = fmaf(wj, bfhi(vr.z), acc_b.y);
                acc_b.z = fmaf(wj, bflo(vr.w), acc_b.z);
                acc_b.w = fmaf(wj, bfhi(vr.w), acc_b.w);
            }
        }
#pragma unroll
        for (int o = 16; o < 64; o <<= 1) {
            acc_a.x += __shfl_xor(acc_a.x, o, 64);
            acc_a.y += __shfl_xor(acc_a.y, o, 64);
            acc_a.z += __shfl_xor(acc_a.z, o, 64);
            acc_a.w += __shfl_xor(acc_a.w, o, 64);
            acc_b.x += __shfl_xor(acc_b.x, o, 64);
            acc_b.y += __shfl_xor(acc_b.y, o, 64);
            acc_b.z += __shfl_xor(acc_b.z, o, 64);
            acc_b.w += __shfl_xor(acc_b.w, o, 64);
        }
        if (g == 0) {
            ((float4*)out)[(size_t)rowi * 32 + s16 * 2] = acc_a;
            ((float4*)out)[(size_t)rowi * 32 + s16 * 2 + 1] = acc_b;
        }
        return;
    }

    // ---- Fallback (deg > 128): lane-per-edge, scores spilled. Rarely taken. ----
    const int end = start + deg;
    const float2* q2r = (const float2*)(q + (size_t)rowi * H);
    const float4* erow = (const float4*)(eigs + (size_t)rowi * ED);
    float m0 = -INFINITY, m1 = -INFINITY;
    for (int e0 = start; e0 < end; e0 += 64) {
        int e = e0 + lane;
        float s0f = -INFINITY, s1f = -INFINITY;
        if (e < end) {
            int x = csr[e];
            int cc = x & COLMASK;
            s1f = pw[(x >> COLBITS) & 7];
            const unsigned* kr = (const unsigned*)(kb + (size_t)cc * H);
            float xx = 0.f;
            for (int t = 0; t < H / 2; t++) {
                unsigned u = kr[t];
                float2 qv = q2r[t];
                xx += qv.x * bflo(u) + qv.y * bfhi(u);
            }
            const float4* crow = (const float4*)(eigs + (size_t)cc * ED);
            float yy = 0.f;
#pragma unroll
            for (int t = 0; t < ED / 4; t++) {
                float4 ev = erow[t], cv = crow[t];
                yy += ev.x * cv.x + ev.y * cv.y + ev.z * cv.z + ev.w * cv.w;
            }
            s0f = xx * inv + el0 * yy;
            spill[e] = s0f;
        }
        m0 = fmaxf(m0, s0f);
        m1 = fmaxf(m1, s1f);
    }
    m0 = wmax64(m0);
    m1 = wmax64(m1);
    float d0 = 0.f, d1 = 0.f;
    for (int e0 = start; e0 < end; e0 += 64) {
        int e = e0 + lane;
        if (e < end) {
            int x = csr[e];
            d0 += __expf(spill[e] - m0);
            d1 += __expf(pw[(x >> COLBITS) & 7] - m1);
        }
    }
    d0 = wsum64(d0);
    d1 = wsum64(d1);
    float r0 = (d0 > 0.f) ? 0.5f / d0 : 0.f;
    float r1 = (d1 > 0.f) ? 0.5f / d1 : 0.f;
    float2 acc2 = make_float2(0.f, 0.f);
    for (int e0 = start; e0 < end; e0 += 64) {
        int cnt2 = min(64, end - e0);
        int cc = 0;
        float wv = 0.f;
        if (lane < cnt2) {
            int e = e0 + lane;
            int x = csr[e];
            cc = x & COLMASK;
            wv = __expf(spill[e] - m0) * r0 + __expf(pw[(x >> COLBITS) & 7] - m1) * r1;
        }
        for (int j = 0; j < cnt2; j++) {
            float wj = __shfl(wv, j, 64);
            int cj = __shfl(cc, j, 64);
            unsigned u = ((const unsigned*)(vb))[(size_t)cj * (H / 2) + lane];
            acc2.x = fmaf(wj, bflo(u), acc2.x);
            acc2.y = fmaf(wj, bfhi(u), acc2.y);
        }
    }
    ((float2*)out)[(size_t)rowi * (H / 2) + lane] = acc2;
}

extern "C" void kernel_launch(void* const* d_in, const int* in_sizes, int n_in,
                              void* d_out, int out_size, void* d_ws, size_t ws_size,
                              hipStream_t stream) {
    const float* q = (const float*)d_in[0];
    const float* k = (const float*)d_in[1];
    const float* v = (const float*)d_in[2];
    const float* eigs = (const float*)d_in[3];
    const float* lambda0 = (const float*)d_in[4];
    const float* pw = (const float*)d_in[5];
    const int* indices = (const int*)d_in[6];
    const int* ptype = (const int*)d_in[7];
    float* out = (float*)d_out;

    int N = in_sizes[0] / H;
    int E = in_sizes[6] / 2;

    char* ws = (char*)d_ws;
    int* cnt = (int*)ws;                 // N (zeroed)
    int* rowstart = cnt + N;             // N+1
    int* partials = rowstart + (N + 1);  // 512
    size_t off = ((size_t)(N + (N + 1) + 512) * 4 + 15) & ~(size_t)15;
    int* rank = (int*)(ws + off);  // E ints; reused as float spill by k_attn fallback
    off += (size_t)E * 4;
    int* csr = (int*)(ws + off);   // E ints, packed (ptype<<17)|col
    off += (size_t)E * 4;
    unsigned short* kb = (unsigned short*)(ws + off);  // N*H bf16
    off += (size_t)N * H * 2;
    unsigned short* vb = (unsigned short*)(ws + off);  // N*H bf16

    hipMemsetAsync(cnt, 0, (size_t)N * sizeof(int), stream);

    int n4 = N * H / 4;
    int nbC = (n4 + 255) / 256;
    k_cast<<<nbC, 256, 0, stream>>>((const float4*)k, (ushort4*)kb, n4);
    k_cast<<<nbC, 256, 0, stream>>>((const float4*)v, (ushort4*)vb, n4);

    int nbE4 = (E / 4 + 255) / 256;
    int nbN = (N + 255) / 256;  // 391 <= 512: single-block partials scan OK
    k_rank<<<nbE4, 256, 0, stream>>>(indices, cnt, rank, E);
    k_scan_blocks<<<nbN, 256, 0, stream>>>(cnt, rowstart, partials, N);
    k_scan_partials<<<1, 512, 0, stream>>>(partials, nbN);
    k_add_offsets<<<nbN, 256, 0, stream>>>(rowstart, partials, N, E);
    k_place<<<nbE4, 256, 0, stream>>>(indices, ptype, rowstart, rank, csr, E);
    k_attn<<<(N + 3) / 4, 256, 0, stream>>>(q, kb, vb, eigs, lambda0, pw, rowstart,
                                            csr, (float*)rank, out, N);
}